// Round 5
// baseline (92.154 us; speedup 1.0000x reference)
//
#include <hip/hip_runtime.h>

#define NB_CAT  8192
#define RANK    16
#define N_COLS  4
#define N_PAIRS 1048576

#define SLICE_BYTES (NB_CAT * 16)                   // 128 KB per column
#define TBL_BYTES   ((size_t)N_COLS * SLICE_BYTES)  // 512 KB
#define LDS_BYTES   (128 * 1024)                    // 2 x 64 KB double buffer

typedef float float2v __attribute__((ext_vector_type(2)));

// Device-pass-only builtin detection (host pass lacks amdgcn builtins).
#if defined(__HIP_DEVICE_COMPILE__) && defined(__has_builtin)
#if __has_builtin(__builtin_amdgcn_cvt_pk_f32_fp8) && __has_builtin(__builtin_amdgcn_cvt_pk_fp8_f32)
#define DEV_FP8_HW 1
#endif
#if __has_builtin(__builtin_amdgcn_global_load_lds)
#define DEV_GLL 1
#endif
#endif

template <int C> __device__ __forceinline__ int comp(const int4& v) {
    if (C == 0) return v.x;
    if (C == 1) return v.y;
    if (C == 2) return v.z;
    return v.w;
}

// ---- e4m3fn software decode/encode (safety net; HW path used on gfx950) ----
__device__ __forceinline__ float sw_dec_fp8(unsigned int b) {
    const unsigned int s = b >> 7, e = (b >> 3) & 0xF, m = b & 7;
    float v;
    if (e == 0) v = (float)m * 0.001953125f;
    else        v = ldexpf((float)(8 + m), (int)e - 10);
    return s ? -v : v;
}
__device__ __forceinline__ unsigned int sw_enc_fp8(float f) {
    const unsigned int s = (__float_as_uint(f) >> 31) << 7;
    float a = fabsf(f);
    if (a > 448.f) a = 448.f;
    float q;
    if (a >= 0.015625f) {
        int ex; const float m = frexpf(a, &ex);
        q = ldexpf(rintf(ldexpf(m, 4)), ex - 4);
    } else {
        q = rintf(a * 512.f) * 0.001953125f;
    }
    if (q == 0.f) return s;
    int ex; const float m = frexpf(q, &ex);
    if (ex - 1 < -6) {
        const unsigned int mm = (unsigned int)rintf(q * 512.f);
        return s | (mm & 7);
    }
    const unsigned int e = (unsigned int)(ex - 1 + 7);
    const unsigned int mm = (unsigned int)rintf(ldexpf(m, 4)) & 7;
    return s | (e << 3) | mm;
}

// HI must be a compile-time constant (builtin selector needs an immediate).
template <bool HI>
__device__ __forceinline__ float2v dec2(unsigned int u) {
#ifdef DEV_FP8_HW
    return __builtin_amdgcn_cvt_pk_f32_fp8((int)u, HI);
#else
    const unsigned int w = HI ? (u >> 16) : u;
    float2v r;
    r.x = sw_dec_fp8(w & 0xFF);
    r.y = sw_dec_fp8((w >> 8) & 0xFF);
    return r;
#endif
}

// Half-row dot: 8 elements (2 dwords). Called h=0 then h=1 per col, in col
// order -> accumulation order identical to the original dot16 -> bit-identical.
__device__ __forceinline__ float dot8_fp8(uint2 A, uint2 B, float acc) {
#define TERM(u, v, SEL)                                                        \
    {                                                                          \
        const float2v a = dec2<SEL>((u));                                      \
        const float2v b = dec2<SEL>((v));                                      \
        acc = fmaf(a.x, b.x, acc);                                             \
        acc = fmaf(a.y, b.y, acc);                                             \
    }
    TERM(A.x, B.x, false) TERM(A.x, B.x, true)
    TERM(A.y, B.y, false) TERM(A.y, B.y, true)
#undef TERM
    return acc;
}

// ---------- prep: fp32 cf -> fp8 e4m3 HALF-ROW table ----------
// Slice k = c*2 + h (64 KB each): 8192 rows x 8 B; row a of slice (c,h) =
// elements 8h..8h+7 of column c, row a.
__global__ __launch_bounds__(256) void pack_fp8_kernel(
    const float4* __restrict__ src, uint4* __restrict__ dst)
{
    const int r = blockIdx.x * 256 + threadIdx.x;   // c*NB_CAT + a, 32768 rows
    const float4 f0 = src[r * 4 + 0];
    const float4 f1 = src[r * 4 + 1];
    const float4 f2 = src[r * 4 + 2];
    const float4 f3 = src[r * 4 + 3];
    uint4 u;
#ifdef DEV_FP8_HW
    int w;
    w = 0;
    w = __builtin_amdgcn_cvt_pk_fp8_f32(f0.x, f0.y, w, false);
    w = __builtin_amdgcn_cvt_pk_fp8_f32(f0.z, f0.w, w, true);
    u.x = (unsigned int)w;
    w = 0;
    w = __builtin_amdgcn_cvt_pk_fp8_f32(f1.x, f1.y, w, false);
    w = __builtin_amdgcn_cvt_pk_fp8_f32(f1.z, f1.w, w, true);
    u.y = (unsigned int)w;
    w = 0;
    w = __builtin_amdgcn_cvt_pk_fp8_f32(f2.x, f2.y, w, false);
    w = __builtin_amdgcn_cvt_pk_fp8_f32(f2.z, f2.w, w, true);
    u.z = (unsigned int)w;
    w = 0;
    w = __builtin_amdgcn_cvt_pk_fp8_f32(f3.x, f3.y, w, false);
    w = __builtin_amdgcn_cvt_pk_fp8_f32(f3.z, f3.w, w, true);
    u.w = (unsigned int)w;
#else
    u.x = sw_enc_fp8(f0.x) | (sw_enc_fp8(f0.y) << 8) | (sw_enc_fp8(f0.z) << 16) | (sw_enc_fp8(f0.w) << 24);
    u.y = sw_enc_fp8(f1.x) | (sw_enc_fp8(f1.y) << 8) | (sw_enc_fp8(f1.z) << 16) | (sw_enc_fp8(f1.w) << 24);
    u.z = sw_enc_fp8(f2.x) | (sw_enc_fp8(f2.y) << 8) | (sw_enc_fp8(f2.z) << 16) | (sw_enc_fp8(f2.w) << 24);
    u.w = sw_enc_fp8(f3.x) | (sw_enc_fp8(f3.y) << 8) | (sw_enc_fp8(f3.z) << 16) | (sw_enc_fp8(f3.w) << 24);
#endif
    const int c = r >> 13;          // NB_CAT = 2^13
    const int a = r & (NB_CAT - 1);
    uint2* d2 = (uint2*)dst;
    uint2 w01; w01.x = u.x; w01.y = u.y;            // elements 0-7
    uint2 w23; w23.x = u.z; w23.y = u.w;            // elements 8-15
    d2[(c << 14) + a]        = w01;                 // slice 2c   (h=0)
    d2[(c << 14) + 8192 + a] = w23;                 // slice 2c+1 (h=1)
}

// ---------- main: 8 phases, 2x64 KB DMA double buffer (r2 = best structure) ----------
// Trims vs r2: (1) x/y issued BEFORE stage DMA (vmcnt retires in order — diag
// no longer serializes behind staging); (2) initial wait is vmcnt(4), so the
// phase-0 gather overlaps stage-1's landing; (3) redundant release barrier
// before the final drain removed (nothing writes buf0 after SR7).
__global__ __launch_bounds__(1024, 1) void IndexKernel_32238024524411_kernel(
    const int4*  __restrict__ x4,
    const int4*  __restrict__ y4,
    const uint4* __restrict__ tbl,   // fp8 half-row table in ws (8 x 64 KB slices)
    const float* __restrict__ stdv,
    float*       __restrict__ out)
{
    extern __shared__ uint4 sh4[];   // 2 x 4096 uint4 = 2 x 64 KB

    const int tid  = threadIdx.x;
    const int base = blockIdx.x * 4096 + tid;

#ifdef DEV_GLL
#define STAGE(K)                                                               \
    {                                                                          \
        const uint4* s_ = tbl + (size_t)(K) * 4096;                            \
        uint4* d_ = sh4 + (((K) & 1) ? 4096 : 0);                              \
        _Pragma("unroll")                                                      \
        for (int it = 0; it < 4; ++it) {                                       \
            __builtin_amdgcn_global_load_lds(                                  \
                (const __attribute__((address_space(1))) unsigned int*)(s_ + it * 1024 + tid), \
                (__attribute__((address_space(3))) unsigned int*)(d_ + it * 1024 + tid),       \
                16, 0, 0);                                                     \
        }                                                                      \
    }
#else
#define STAGE(K)                                                               \
    {                                                                          \
        const uint4* s_ = tbl + (size_t)(K) * 4096;                            \
        uint4* d_ = sh4 + (((K) & 1) ? 4096 : 0);                              \
        _Pragma("unroll")                                                      \
        for (int it = 0; it < 4; ++it) d_[it * 1024 + tid] = s_[it * 1024 + tid]; \
    }
#endif

    // x/y first: oldest in the vmcnt queue -> the diag pass consumes them
    // without waiting behind stage DMA (in-order vmcnt retirement).
    int4 xv[4], yv[4];
#pragma unroll
    for (int j = 0; j < 4; ++j) {
        xv[j] = x4[base + j * 1024];
        yv[j] = y4[base + j * 1024];
    }
    asm volatile("" ::: "memory");   // pin issue order: x/y before stage DMA

    STAGE(0) STAGE(1)

    float acc[4] = {0.f, 0.f, 0.f, 0.f};

    // diagonal std^2 pre-pass (exact fp32) — overlaps with staging in flight;
    // stdv loads are exec-masked rare (hit prob 1/8192 per col).
#pragma unroll
    for (int j = 0; j < 4; ++j) {
        const int4 a = xv[j], b = yv[j];
        if (a.x == b.x) { const float s = stdv[0 * NB_CAT + a.x]; acc[j] = fmaf(s, s, acc[j]); }
        if (a.y == b.y) { const float s = stdv[1 * NB_CAT + a.y]; acc[j] = fmaf(s, s, acc[j]); }
        if (a.z == b.z) { const float s = stdv[2 * NB_CAT + a.z]; acc[j] = fmaf(s, s, acc[j]); }
        if (a.w == b.w) { const float s = stdv[3 * NB_CAT + a.w]; acc[j] = fmaf(s, s, acc[j]); }
    }

    // counted wait: <=4 outstanding -> stage 0 landed (in-order retire);
    // stage 1 may still be in flight and lands under the phase-0 gather.
    asm volatile("s_waitcnt vmcnt(4)" ::: "memory");
    __builtin_amdgcn_s_barrier();
    asm volatile("" ::: "memory");

#define GATHER(K)                                                              \
    {                                                                          \
        constexpr int c_ = (K) >> 1;                                           \
        const uint2* bp = (const uint2*)(sh4 + (((K) & 1) ? 4096 : 0));        \
        _Pragma("unroll")                                                      \
        for (int j = 0; j < 4; ++j) {                                          \
            const int a_ = comp<c_>(xv[j]);                                    \
            const int b_ = comp<c_>(yv[j]);                                    \
            const uint2 Av = bp[a_];                                           \
            const uint2 Bv = bp[b_];                                           \
            acc[j] = dot8_fp8(Av, Bv, acc[j]);                                 \
        }                                                                      \
    }

    // barrier: all waves done reading the buffer about to be overwritten;
    // STAGE it; vmcnt(4): previous stage (older, in-order) fully landed;
    // barrier: cross-wave visibility of that landing.
#define SYNC_REFILL(KNEXT)                                                     \
    __builtin_amdgcn_s_barrier();                                              \
    asm volatile("" ::: "memory");                                             \
    STAGE(KNEXT)                                                               \
    asm volatile("s_waitcnt vmcnt(4)" ::: "memory");                           \
    __builtin_amdgcn_s_barrier();                                              \
    asm volatile("" ::: "memory");

    GATHER(0)
    SYNC_REFILL(2)
    GATHER(1)
    SYNC_REFILL(3)
    GATHER(2)
    SYNC_REFILL(4)
    GATHER(3)
    SYNC_REFILL(5)
    GATHER(4)
    SYNC_REFILL(6)
    GATHER(5)
    SYNC_REFILL(7)
    GATHER(6)
    // final drain: no release barrier needed (buf0 is never written again);
    // vmcnt(0) = own stage-7 loads done, barrier = all waves' done.
    asm volatile("s_waitcnt vmcnt(0)" ::: "memory");
    __builtin_amdgcn_s_barrier();
    asm volatile("" ::: "memory");
    GATHER(7)

#undef SYNC_REFILL
#undef GATHER
#undef STAGE

#pragma unroll
    for (int j = 0; j < 4; ++j) {
        out[base + j * 1024] = acc[j];
    }
}

// ---------- fallback (fp32 direct gather, R3 structure) if ws too small ----------
__global__ __launch_bounds__(256) void fallback_kernel(
    const int* __restrict__ x, const int* __restrict__ y,
    const float4* __restrict__ cf, const float* __restrict__ stdv,
    float* __restrict__ out)
{
    const int tid = threadIdx.x;
    const int q = tid & 15, gi = tid >> 4, c = q >> 2, s = q & 3;
    const int p0 = blockIdx.x * 32 + gi, p1 = p0 + 16;
    const int rb = c * NB_CAT;
    const int xi0 = x[p0*4+c], yi0 = y[p0*4+c], xi1 = x[p1*4+c], yi1 = y[p1*4+c];
    const float4 a0 = cf[(size_t)(rb+xi0)*4 + s], b0 = cf[(size_t)(rb+yi0)*4 + s];
    const float4 a1 = cf[(size_t)(rb+xi1)*4 + s], b1 = cf[(size_t)(rb+yi1)*4 + s];
    float v0 = a0.x*b0.x; v0 = fmaf(a0.y,b0.y,v0); v0 = fmaf(a0.z,b0.z,v0); v0 = fmaf(a0.w,b0.w,v0);
    float v1 = a1.x*b1.x; v1 = fmaf(a1.y,b1.y,v1); v1 = fmaf(a1.z,b1.z,v1); v1 = fmaf(a1.w,b1.w,v1);
    if (s == 0 && xi0 == yi0) { float sd = stdv[rb+xi0]; v0 = fmaf(sd,sd,v0); }
    if (s == 0 && xi1 == yi1) { float sd = stdv[rb+yi1]; v1 = fmaf(sd,sd,v1); }
    int t;
    t = __builtin_amdgcn_update_dpp(0, __float_as_int(v0), 0xB1, 0xF, 0xF, true); v0 += __int_as_float(t);
    t = __builtin_amdgcn_update_dpp(0, __float_as_int(v0), 0x4E, 0xF, 0xF, true); v0 += __int_as_float(t);
    t = __builtin_amdgcn_update_dpp(0, __float_as_int(v0), 0x141,0xF, 0xF, true); v0 += __int_as_float(t);
    t = __builtin_amdgcn_update_dpp(0, __float_as_int(v0), 0x128,0xF, 0xF, true); v0 += __int_as_float(t);
    t = __builtin_amdgcn_update_dpp(0, __float_as_int(v1), 0xB1, 0xF, 0xF, true); v1 += __int_as_float(t);
    t = __builtin_amdgcn_update_dpp(0, __float_as_int(v1), 0x4E, 0xF, 0xF, true); v1 += __int_as_float(t);
    t = __builtin_amdgcn_update_dpp(0, __float_as_int(v1), 0x141,0xF, 0xF, true); v1 += __int_as_float(t);
    t = __builtin_amdgcn_update_dpp(0, __float_as_int(v1), 0x128,0xF, 0xF, true); v1 += __int_as_float(t);
    if (q == 0) { out[p0] = v0; out[p1] = v1; }
}

extern "C" void kernel_launch(void* const* d_in, const int* in_sizes, int n_in,
                              void* d_out, int out_size, void* d_ws, size_t ws_size,
                              hipStream_t stream) {
    const int*   x    = (const int*)d_in[0];
    const int*   y    = (const int*)d_in[1];
    const float* cf   = (const float*)d_in[2];
    const float* stdv = (const float*)d_in[3];
    float*       out  = (float*)d_out;

    // Host gating depends ONLY on ws_size (R15 lesson).
    if (ws_size < TBL_BYTES) {
        fallback_kernel<<<N_PAIRS / 32, 256, 0, stream>>>(
            x, y, (const float4*)cf, stdv, out);
        return;
    }

    (void)hipFuncSetAttribute(
        reinterpret_cast<const void*>(&IndexKernel_32238024524411_kernel),
        hipFuncAttributeMaxDynamicSharedMemorySize, LDS_BYTES);

    pack_fp8_kernel<<<N_COLS * NB_CAT / 256, 256, 0, stream>>>(
        (const float4*)cf, (uint4*)d_ws);

    IndexKernel_32238024524411_kernel<<<N_PAIRS / 4096, 1024, LDS_BYTES, stream>>>(
        (const int4*)x, (const int4*)y, (const uint4*)d_ws, stdv, out);
}

// Round 6
// 88.300 us; speedup vs baseline: 1.0436x; 1.0436x over previous
//
#include <hip/hip_runtime.h>

#define NB_CAT  8192
#define RANK    16
#define N_COLS  4
#define N_PAIRS 1048576

#define SLICE_BYTES (NB_CAT * 16)                   // 128 KB per column
#define TBL_BYTES   ((size_t)N_COLS * SLICE_BYTES)  // 512 KB
#define LDS_BYTES   (128 * 1024)                    // 2 x 64 KB double buffer

typedef float float2v __attribute__((ext_vector_type(2)));

// Device-pass-only builtin detection (host pass lacks amdgcn builtins).
#if defined(__HIP_DEVICE_COMPILE__) && defined(__has_builtin)
#if __has_builtin(__builtin_amdgcn_cvt_pk_f32_fp8) && __has_builtin(__builtin_amdgcn_cvt_pk_fp8_f32)
#define DEV_FP8_HW 1
#endif
#if __has_builtin(__builtin_amdgcn_global_load_lds)
#define DEV_GLL 1
#endif
#endif

template <int C> __device__ __forceinline__ int comp(const int4& v) {
    if (C == 0) return v.x;
    if (C == 1) return v.y;
    if (C == 2) return v.z;
    return v.w;
}

// ---- e4m3fn software decode/encode (safety net; HW path used on gfx950) ----
__device__ __forceinline__ float sw_dec_fp8(unsigned int b) {
    const unsigned int s = b >> 7, e = (b >> 3) & 0xF, m = b & 7;
    float v;
    if (e == 0) v = (float)m * 0.001953125f;
    else        v = ldexpf((float)(8 + m), (int)e - 10);
    return s ? -v : v;
}
__device__ __forceinline__ unsigned int sw_enc_fp8(float f) {
    const unsigned int s = (__float_as_uint(f) >> 31) << 7;
    float a = fabsf(f);
    if (a > 448.f) a = 448.f;
    float q;
    if (a >= 0.015625f) {
        int ex; const float m = frexpf(a, &ex);
        q = ldexpf(rintf(ldexpf(m, 4)), ex - 4);
    } else {
        q = rintf(a * 512.f) * 0.001953125f;
    }
    if (q == 0.f) return s;
    int ex; const float m = frexpf(q, &ex);
    if (ex - 1 < -6) {
        const unsigned int mm = (unsigned int)rintf(q * 512.f);
        return s | (mm & 7);
    }
    const unsigned int e = (unsigned int)(ex - 1 + 7);
    const unsigned int mm = (unsigned int)rintf(ldexpf(m, 4)) & 7;
    return s | (e << 3) | mm;
}

// HI must be a compile-time constant (builtin selector needs an immediate).
template <bool HI>
__device__ __forceinline__ float2v dec2(unsigned int u) {
#ifdef DEV_FP8_HW
    return __builtin_amdgcn_cvt_pk_f32_fp8((int)u, HI);
#else
    const unsigned int w = HI ? (u >> 16) : u;
    float2v r;
    r.x = sw_dec_fp8(w & 0xFF);
    r.y = sw_dec_fp8((w >> 8) & 0xFF);
    return r;
#endif
}

// Half-row dot: 8 elements (2 dwords). Accumulation order matches the previous
// full-row dot16 when called h=0 then h=1 -> bit-identical result.
__device__ __forceinline__ float dot8_fp8(uint2 A, uint2 B, float acc) {
#define TERM(u, v, SEL)                                                        \
    {                                                                          \
        const float2v a = dec2<SEL>((u));                                      \
        const float2v b = dec2<SEL>((v));                                      \
        acc = fmaf(a.x, b.x, acc);                                             \
        acc = fmaf(a.y, b.y, acc);                                             \
    }
    TERM(A.x, B.x, false) TERM(A.x, B.x, true)
    TERM(A.y, B.y, false) TERM(A.y, B.y, true)
#undef TERM
    return acc;
}

// ---------- prep: fp32 cf -> fp8 e4m3 HALF-ROW table ----------
// Slice k = c*2 + h (64 KB each, contiguous): 8192 rows x 8 B, row a of slice
// (c,h) = bytes 8h..8h+7 of the rank-16 fp8 row (elements 8h..8h+7).
__global__ __launch_bounds__(256) void pack_fp8_kernel(
    const float4* __restrict__ src, uint4* __restrict__ dst)
{
    const int r = blockIdx.x * 256 + threadIdx.x;   // c*NB_CAT + a, 32768 rows
    const float4 f0 = src[r * 4 + 0];
    const float4 f1 = src[r * 4 + 1];
    const float4 f2 = src[r * 4 + 2];
    const float4 f3 = src[r * 4 + 3];
    uint4 u;
#ifdef DEV_FP8_HW
    int w;
    w = 0;
    w = __builtin_amdgcn_cvt_pk_fp8_f32(f0.x, f0.y, w, false);
    w = __builtin_amdgcn_cvt_pk_fp8_f32(f0.z, f0.w, w, true);
    u.x = (unsigned int)w;
    w = 0;
    w = __builtin_amdgcn_cvt_pk_fp8_f32(f1.x, f1.y, w, false);
    w = __builtin_amdgcn_cvt_pk_fp8_f32(f1.z, f1.w, w, true);
    u.y = (unsigned int)w;
    w = 0;
    w = __builtin_amdgcn_cvt_pk_fp8_f32(f2.x, f2.y, w, false);
    w = __builtin_amdgcn_cvt_pk_fp8_f32(f2.z, f2.w, w, true);
    u.z = (unsigned int)w;
    w = 0;
    w = __builtin_amdgcn_cvt_pk_fp8_f32(f3.x, f3.y, w, false);
    w = __builtin_amdgcn_cvt_pk_fp8_f32(f3.z, f3.w, w, true);
    u.w = (unsigned int)w;
#else
    u.x = sw_enc_fp8(f0.x) | (sw_enc_fp8(f0.y) << 8) | (sw_enc_fp8(f0.z) << 16) | (sw_enc_fp8(f0.w) << 24);
    u.y = sw_enc_fp8(f1.x) | (sw_enc_fp8(f1.y) << 8) | (sw_enc_fp8(f1.z) << 16) | (sw_enc_fp8(f1.w) << 24);
    u.z = sw_enc_fp8(f2.x) | (sw_enc_fp8(f2.y) << 8) | (sw_enc_fp8(f2.z) << 16) | (sw_enc_fp8(f2.w) << 24);
    u.w = sw_enc_fp8(f3.x) | (sw_enc_fp8(f3.y) << 8) | (sw_enc_fp8(f3.z) << 16) | (sw_enc_fp8(f3.w) << 24);
#endif
    const int c = r >> 13;          // NB_CAT = 2^13
    const int a = r & (NB_CAT - 1);
    uint2* d2 = (uint2*)dst;
    uint2 w01; w01.x = u.x; w01.y = u.y;            // elements 0-7
    uint2 w23; w23.x = u.z; w23.y = u.w;            // elements 8-15
    d2[(c << 14) + a]        = w01;                 // slice 2c   (h=0)
    d2[(c << 14) + 8192 + a] = w23;                 // slice 2c+1 (h=1)
}

// ---------- main: 8 phases (col x half-row), 2x64 KB LDS double buffer ----------
// 256 blocks x 1024 threads. Staging is pure global_load_lds DMA into the idle
// buffer (no VGPR round-trip, no ds_write pass, no lgkm staging drain). Per
// phase sync: barrier (release buf) -> issue 4 DMA loads -> vmcnt(4) counted
// wait (previous stage only; it had a whole phase to land) -> barrier.
// Gather: one ds_read_b64 per operand (random row, 8 B).
// This is the best-measured structure of the session (88.8 us, r2).
__global__ __launch_bounds__(1024, 1) void IndexKernel_32238024524411_kernel(
    const int4*  __restrict__ x4,
    const int4*  __restrict__ y4,
    const uint4* __restrict__ tbl,   // fp8 half-row table in ws (8 x 64 KB slices)
    const float* __restrict__ stdv,
    float*       __restrict__ out)
{
    extern __shared__ uint4 sh4[];   // 2 x 4096 uint4 = 2 x 64 KB

    const int tid  = threadIdx.x;
    const int base = blockIdx.x * 4096 + tid;

#ifdef DEV_GLL
#define STAGE(K)                                                               \
    {                                                                          \
        const uint4* s_ = tbl + (size_t)(K) * 4096;                            \
        uint4* d_ = sh4 + (((K) & 1) ? 4096 : 0);                              \
        _Pragma("unroll")                                                      \
        for (int it = 0; it < 4; ++it) {                                       \
            __builtin_amdgcn_global_load_lds(                                  \
                (const __attribute__((address_space(1))) unsigned int*)(s_ + it * 1024 + tid), \
                (__attribute__((address_space(3))) unsigned int*)(d_ + it * 1024 + tid),       \
                16, 0, 0);                                                     \
        }                                                                      \
    }
#else
#define STAGE(K)                                                               \
    {                                                                          \
        const uint4* s_ = tbl + (size_t)(K) * 4096;                            \
        uint4* d_ = sh4 + (((K) & 1) ? 4096 : 0);                              \
        _Pragma("unroll")                                                      \
        for (int it = 0; it < 4; ++it) d_[it * 1024 + tid] = s_[it * 1024 + tid]; \
    }
#endif

    // issue stage 0 and 1 first — both buffers fill while we load x/y and run
    // the diag pre-pass.
    STAGE(0) STAGE(1)

    int4 xv[4], yv[4];
#pragma unroll
    for (int j = 0; j < 4; ++j) {
        xv[j] = x4[base + j * 1024];
        yv[j] = y4[base + j * 1024];
    }

    float acc[4] = {0.f, 0.f, 0.f, 0.f};

    // diagonal std^2 pre-pass (exact fp32) — overlaps with staging in flight
#pragma unroll
    for (int j = 0; j < 4; ++j) {
        const int4 a = xv[j], b = yv[j];
        if (a.x == b.x) { const float s = stdv[0 * NB_CAT + a.x]; acc[j] = fmaf(s, s, acc[j]); }
        if (a.y == b.y) { const float s = stdv[1 * NB_CAT + a.y]; acc[j] = fmaf(s, s, acc[j]); }
        if (a.z == b.z) { const float s = stdv[2 * NB_CAT + a.z]; acc[j] = fmaf(s, s, acc[j]); }
        if (a.w == b.w) { const float s = stdv[3 * NB_CAT + a.w]; acc[j] = fmaf(s, s, acc[j]); }
    }

    // drain everything once (stages 0+1, x/y, stdv) + sync
    asm volatile("s_waitcnt vmcnt(0) lgkmcnt(0)" ::: "memory");
    __builtin_amdgcn_s_barrier();
    asm volatile("" ::: "memory");

#define GATHER(K)                                                              \
    {                                                                          \
        constexpr int c_ = (K) >> 1;                                           \
        const uint2* bp = (const uint2*)(sh4 + (((K) & 1) ? 4096 : 0));        \
        _Pragma("unroll")                                                      \
        for (int j = 0; j < 4; ++j) {                                          \
            const int a_ = comp<c_>(xv[j]);                                    \
            const int b_ = comp<c_>(yv[j]);                                    \
            const uint2 Av = bp[a_];                                           \
            const uint2 Bv = bp[b_];                                           \
            acc[j] = dot8_fp8(Av, Bv, acc[j]);                                 \
        }                                                                      \
    }

    // barrier: all waves done reading buf[(K+2)&1]; then refill it; counted
    // vmcnt keeps only the just-issued stage in flight; barrier: everyone's
    // previous stage has landed.
#define SYNC_REFILL(KNEXT)                                                     \
    __builtin_amdgcn_s_barrier();                                              \
    asm volatile("" ::: "memory");                                             \
    STAGE(KNEXT)                                                               \
    asm volatile("s_waitcnt vmcnt(4)" ::: "memory");                           \
    __builtin_amdgcn_s_barrier();                                              \
    asm volatile("" ::: "memory");

    GATHER(0)
    SYNC_REFILL(2)
    GATHER(1)
    SYNC_REFILL(3)
    GATHER(2)
    SYNC_REFILL(4)
    GATHER(3)
    SYNC_REFILL(5)
    GATHER(4)
    SYNC_REFILL(6)
    GATHER(5)
    SYNC_REFILL(7)
    GATHER(6)
    // final: nothing left to issue; drain stage 7 fully
    __builtin_amdgcn_s_barrier();
    asm volatile("s_waitcnt vmcnt(0)" ::: "memory");
    __builtin_amdgcn_s_barrier();
    asm volatile("" ::: "memory");
    GATHER(7)

#undef SYNC_REFILL
#undef GATHER
#undef STAGE

#pragma unroll
    for (int j = 0; j < 4; ++j) {
        out[base + j * 1024] = acc[j];
    }
}

// ---------- fallback (fp32 direct gather, R3 structure) if ws too small ----------
__global__ __launch_bounds__(256) void fallback_kernel(
    const int* __restrict__ x, const int* __restrict__ y,
    const float4* __restrict__ cf, const float* __restrict__ stdv,
    float* __restrict__ out)
{
    const int tid = threadIdx.x;
    const int q = tid & 15, gi = tid >> 4, c = q >> 2, s = q & 3;
    const int p0 = blockIdx.x * 32 + gi, p1 = p0 + 16;
    const int rb = c * NB_CAT;
    const int xi0 = x[p0*4+c], yi0 = y[p0*4+c], xi1 = x[p1*4+c], yi1 = y[p1*4+c];
    const float4 a0 = cf[(size_t)(rb+xi0)*4 + s], b0 = cf[(size_t)(rb+yi0)*4 + s];
    const float4 a1 = cf[(size_t)(rb+xi1)*4 + s], b1 = cf[(size_t)(rb+yi1)*4 + s];
    float v0 = a0.x*b0.x; v0 = fmaf(a0.y,b0.y,v0); v0 = fmaf(a0.z,b0.z,v0); v0 = fmaf(a0.w,b0.w,v0);
    float v1 = a1.x*b1.x; v1 = fmaf(a1.y,b1.y,v1); v1 = fmaf(a1.z,b1.z,v1); v1 = fmaf(a1.w,b1.w,v1);
    if (s == 0 && xi0 == yi0) { float sd = stdv[rb+xi0]; v0 = fmaf(sd,sd,v0); }
    if (s == 0 && xi1 == yi1) { float sd = stdv[rb+yi1]; v1 = fmaf(sd,sd,v1); }
    int t;
    t = __builtin_amdgcn_update_dpp(0, __float_as_int(v0), 0xB1, 0xF, 0xF, true); v0 += __int_as_float(t);
    t = __builtin_amdgcn_update_dpp(0, __float_as_int(v0), 0x4E, 0xF, 0xF, true); v0 += __int_as_float(t);
    t = __builtin_amdgcn_update_dpp(0, __float_as_int(v0), 0x141,0xF, 0xF, true); v0 += __int_as_float(t);
    t = __builtin_amdgcn_update_dpp(0, __float_as_int(v0), 0x128,0xF, 0xF, true); v0 += __int_as_float(t);
    t = __builtin_amdgcn_update_dpp(0, __float_as_int(v1), 0xB1, 0xF, 0xF, true); v1 += __int_as_float(t);
    t = __builtin_amdgcn_update_dpp(0, __float_as_int(v1), 0x4E, 0xF, 0xF, true); v1 += __int_as_float(t);
    t = __builtin_amdgcn_update_dpp(0, __float_as_int(v1), 0x141,0xF, 0xF, true); v1 += __int_as_float(t);
    t = __builtin_amdgcn_update_dpp(0, __float_as_int(v1), 0x128,0xF, 0xF, true); v1 += __int_as_float(t);
    if (q == 0) { out[p0] = v0; out[p1] = v1; }
}

extern "C" void kernel_launch(void* const* d_in, const int* in_sizes, int n_in,
                              void* d_out, int out_size, void* d_ws, size_t ws_size,
                              hipStream_t stream) {
    const int*   x    = (const int*)d_in[0];
    const int*   y    = (const int*)d_in[1];
    const float* cf   = (const float*)d_in[2];
    const float* stdv = (const float*)d_in[3];
    float*       out  = (float*)d_out;

    // Host gating depends ONLY on ws_size (R15 lesson).
    if (ws_size < TBL_BYTES) {
        fallback_kernel<<<N_PAIRS / 32, 256, 0, stream>>>(
            x, y, (const float4*)cf, stdv, out);
        return;
    }

    (void)hipFuncSetAttribute(
        reinterpret_cast<const void*>(&IndexKernel_32238024524411_kernel),
        hipFuncAttributeMaxDynamicSharedMemorySize, LDS_BYTES);

    pack_fp8_kernel<<<N_COLS * NB_CAT / 256, 256, 0, stream>>>(
        (const float4*)cf, (uint4*)d_ws);

    IndexKernel_32238024524411_kernel<<<N_PAIRS / 4096, 1024, LDS_BYTES, stream>>>(
        (const int4*)x, (const int4*)y, (const uint4*)d_ws, stdv, out);
}